// Round 12
// baseline (288.225 us; speedup 1.0000x reference)
//
#include <hip/hip_runtime.h>

// SupProtoConLoss on MI355X — round 12.
// R11 post-mortem: flat unroll-1 loop recomputed LDS addrs (VALU 23->34%) and
// the reorder didn't beat R7's 110.5us engine; the win came from node-trim
// (~30us/node). Round 12: (1) engine reverted to R7 verbatim (nested jt/ch,
// 2-barrier, immediate offsets); (2) k_final fused into k_row via a
// LAST-BLOCK pattern (atomic done-counter; no cooperative launch, no
// co-residency or dispatch-order assumption): finalizing block reads row sums
// with atomicAdd(p,0.0f) — device-coherent, immune to per-XCD L2 staleness.
// done counter zeroed in k_prep (kernel-boundary coherence). 2 graph nodes.
// LDS stays exactly 81920 (finalize reuses As) -> 2 blocks/CU preserved.

#define NROW 8192
#define DDIM 512
#define NCLS 100
#define PANEL 64
#define JT 256  // cols per j-tile (4 waves x 64)
#define BK 32

typedef float f32x4 __attribute__((ext_vector_type(4)));
typedef short s16x8 __attribute__((ext_vector_type(8)));

#define GLOBAL_AS __attribute__((address_space(1)))
#define LDS_AS __attribute__((address_space(3)))

__device__ __forceinline__ unsigned short f2bf(float x) {
  unsigned int u = __builtin_bit_cast(unsigned int, x);
  u += 0x7FFFu + ((u >> 16) & 1u);  // round-to-nearest-even
  return (unsigned short)(u >> 16);
}

// One wave per row: L2-norm, scale, cast to bf16. Also zeroes row_pos/row_neg
// (16384 floats over 2048 blocks) and the done counter.
__global__ void __launch_bounds__(256) k_prep(
    const float* __restrict__ reps, float* __restrict__ row_pos,
    unsigned short* __restrict__ Rb, int* __restrict__ done) {
  const int wave = threadIdx.x >> 6;
  const int lane = threadIdx.x & 63;
  const int row = blockIdx.x * 4 + wave;
  if (threadIdx.x < 8) row_pos[blockIdx.x * 8 + threadIdx.x] = 0.0f;
  if (blockIdx.x == 0 && threadIdx.x == 0) *done = 0;
  const float* r = reps + (size_t)row * DDIM;
  float4 v0 = *(const float4*)(r + lane * 4);
  float4 v1 = *(const float4*)(r + 256 + lane * 4);
  float ss = v0.x * v0.x + v0.y * v0.y + v0.z * v0.z + v0.w * v0.w +
             v1.x * v1.x + v1.y * v1.y + v1.z * v1.z + v1.w * v1.w;
#pragma unroll
  for (int m = 1; m < 64; m <<= 1) ss += __shfl_xor(ss, m);
  const float scale = 1.0f / sqrtf(ss);  // norms ~22.6; 1e-8 clamp unreachable
  ushort4 a, b;
  a.x = f2bf(v0.x * scale); a.y = f2bf(v0.y * scale);
  a.z = f2bf(v0.z * scale); a.w = f2bf(v0.w * scale);
  b.x = f2bf(v1.x * scale); b.y = f2bf(v1.y * scale);
  b.z = f2bf(v1.z * scale); b.w = f2bf(v1.w * scale);
  *(ushort4*)(Rb + (size_t)row * DDIM + lane * 4) = a;
  *(ushort4*)(Rb + (size_t)row * DDIM + 256 + lane * 4) = b;
}

// Block = 64-row panel (p = bx>>2) x 2048-col slice (s = bx&3), 4 waves.
// Wave tile per jt: 64 rows x 64 cols = 4a x 4b of 16x16x32 MFMA.
// Last block to finish runs the loss finalize in-kernel.
__global__ void __launch_bounds__(256) k_row(
    const unsigned short* __restrict__ Rb, const int* __restrict__ labels,
    float* __restrict__ row_pos, float* __restrict__ row_neg,
    int* __restrict__ done, float* __restrict__ out) {
  const int bx = blockIdx.x;
  const int p = bx >> 2;   // row panel 0..127
  const int s = bx & 3;    // j slice 0..3 (fixed per XCD under %8 dispatch)
  const int i0 = p * PANEL;
  const int j0s = s * 2048;

  // As chunk-major [ch][row][k-in-chunk] (row stride 64B), 64 KB; Bs 16 KB.
  // Total 81920 B exactly -> 2 blocks/CU. Bs = epilogue scratch; As = finalize
  // scratch. DO NOT add LDS.
  __shared__ __attribute__((aligned(16))) unsigned short As[16][PANEL][BK];
  __shared__ __attribute__((aligned(16))) unsigned short Bs[JT * BK];
  __shared__ int islast;

  const int tid = threadIdx.x;
  const int lane = tid & 63;
  const int wave = tid >> 6;
  const int quad = lane >> 4, c16 = lane & 15;

  // ---- Stage A panel once, chunk-major: 64 instrs, 16 per wave.
#pragma unroll
  for (int t = 0; t < 16; ++t) {
    const int ii = wave * 16 + t;        // wave-uniform, 0..63
    const int ch = ii >> 2;
    const int rg = (ii & 3) * 16;
    const unsigned short* src =
        Rb + (size_t)(i0 + rg + (lane >> 2)) * DDIM + ch * BK + (lane & 3) * 8;
    __builtin_amdgcn_global_load_lds(
        (GLOBAL_AS void*)const_cast<unsigned short*>(src),
        (LDS_AS void*)(&As[ch][rg][0]), 16, 0, 0);
  }

  // Per-lane row labels and running row sums (live across the whole sweep).
  int li16[16];
  float ps16[16], ns16[16];
#pragma unroll
  for (int a = 0; a < 4; ++a)
#pragma unroll
    for (int r = 0; r < 4; ++r) {
      li16[a * 4 + r] = labels[i0 + a * 16 + quad * 4 + r];
      ps16[a * 4 + r] = 0.0f;
      ns16[a * 4 + r] = 0.0f;
    }

  const float C0 = -5.0f + 1e-7f;  // s = 5g - 5 + 1e-7 (static shift S=10)

  for (int jt = 0; jt < 8; ++jt) {
    const int j0 = j0s + jt * JT;
    int lj[4], gj[4];
#pragma unroll
    for (int b = 0; b < 4; ++b) {
      gj[b] = j0 + wave * 64 + b * 16 + c16;
      lj[b] = labels[gj[b]];
    }

    f32x4 acc[4][4];
#pragma unroll
    for (int a = 0; a < 4; ++a)
#pragma unroll
      for (int b = 0; b < 4; ++b) acc[a][b] = (f32x4)0.0f;

    for (int ch = 0; ch < 16; ++ch) {
      __syncthreads();  // Bs consumed (also drains A staging before 1st use)
#pragma unroll
      for (int t = 0; t < 4; ++t) {
        const int cb = wave * 64 + t * 256;  // wave-uniform
        const int sl = cb + lane;            // jcol = sl>>2, kc = sl&3
        const unsigned short* src =
            Rb + (size_t)(j0 + (sl >> 2)) * DDIM + ch * BK + (sl & 3) * 8;
        __builtin_amdgcn_global_load_lds(
            (GLOBAL_AS void*)const_cast<unsigned short*>(src),
            (LDS_AS void*)(Bs + cb * 8), 16, 0, 0);
      }
      __syncthreads();  // Bs ready

      s16x8 af[4], bfr[4];
#pragma unroll
      for (int a = 0; a < 4; ++a)
        af[a] = *(const s16x8*)(&As[ch][a * 16 + c16][quad * 8]);
#pragma unroll
      for (int b = 0; b < 4; ++b)
        bfr[b] = *(const s16x8*)(Bs + (wave * 64 + b * 16 + c16) * BK + quad * 8);
#pragma unroll
      for (int a = 0; a < 4; ++a)
#pragma unroll
        for (int b = 0; b < 4; ++b)
          acc[a][b] = __builtin_amdgcn_mfma_f32_16x16x32_bf16(af[a], bfr[b],
                                                              acc[a][b], 0, 0, 0);
    }

    // Fold this j-tile into register row sums (no atomics).
#pragma unroll
    for (int a = 0; a < 4; ++a) {
#pragma unroll
      for (int r = 0; r < 4; ++r) {
        const int gi = i0 + a * 16 + quad * 4 + r;
        const int li = li16[a * 4 + r];
        float ps = 0.0f, ns = 0.0f;
#pragma unroll
        for (int b = 0; b < 4; ++b) {
          const float g = acc[a][b][r];
          const float sv = fmaf(g, 5.0f, C0);
          const float ev = __expf(sv);
          const bool same = (li == lj[b]);
          ps += (same && gi != gj[b]) ? sv : 0.0f;
          ns += same ? 0.0f : ev;
        }
        ps16[a * 4 + r] += ps;
        ns16[a * 4 + r] += ns;
      }
    }
  }

  // ---- Block epilogue: reduce per-lane sums -> 64 rows, 2 atomics each.
  __syncthreads();
  float* rp = (float*)Bs;   // 64 floats
  float* rn = rp + 64;
  if (tid < 128) rp[tid] = 0.0f;
  __syncthreads();
#pragma unroll
  for (int a = 0; a < 4; ++a) {
#pragma unroll
    for (int r = 0; r < 4; ++r) {
      float ps = ps16[a * 4 + r], ns = ns16[a * 4 + r];
#pragma unroll
      for (int m = 1; m < 16; m <<= 1) {  // reduce across the 16 c16 lanes
        ps += __shfl_xor(ps, m);
        ns += __shfl_xor(ns, m);
      }
      if (c16 == 0) {  // 4-way wave contention, once per block: trivial
        atomicAdd(&rp[a * 16 + quad * 4 + r], ps);
        atomicAdd(&rn[a * 16 + quad * 4 + r], ns);
      }
    }
  }
  __syncthreads();
  if (tid < 64) {
    atomicAdd(&row_pos[i0 + tid], rp[tid]);   // 4 adds per address chip-wide
    atomicAdd(&row_neg[i0 + tid], rn[tid]);
  }

  // ---- Last-block finalize (no co-residency / dispatch-order assumption).
  __threadfence();  // release: row atomics ordered before counter increment
  if (tid == 0) islast = (atomicAdd(done, 1) == gridDim.x - 1) ? 1 : 0;
  __syncthreads();
  if (islast == 0) return;
  __threadfence();  // acquire side

  int* hcnt = (int*)&As[0][0][0];        // reuse As as finalize scratch
  float* fsum = (float*)&As[1][0][0];    // 4 partial sums
  float* fcnt = fsum + 4;
  if (tid < NCLS) hcnt[tid] = 0;
  __syncthreads();
  for (int i = tid; i < NROW; i += 256) atomicAdd(&hcnt[labels[i]], 1);
  __syncthreads();
  float lsum = 0.0f, lcnt = 0.0f;
  for (int i = tid; i < NROW; i += 256) {
    // atomic reads: device-coherent (plain loads could see stale per-XCD L2)
    const float rpv = atomicAdd(&row_pos[i], 0.0f);
    const float rnv = atomicAdd(&row_neg[i], 0.0f);
    const float c = (float)(hcnt[labels[i]] - 1);
    const float pos = rpv / (c + 1e-8f);
    const float loss = -pos + logf(rnv + 1e-8f);
    if (loss > 0.0f) { lsum += loss; lcnt += 1.0f; }
  }
#pragma unroll
  for (int m = 1; m < 64; m <<= 1) {
    lsum += __shfl_xor(lsum, m);
    lcnt += __shfl_xor(lcnt, m);
  }
  if (lane == 0) { fsum[wave] = lsum; fcnt[wave] = lcnt; }
  __syncthreads();
  if (tid == 0) {
    float S = 0.0f, C = 0.0f;
#pragma unroll
    for (int w = 0; w < 4; ++w) { S += fsum[w]; C += fcnt[w]; }
    out[0] = S / (C + 1e-8f);
  }
}

extern "C" void kernel_launch(void* const* d_in, const int* in_sizes, int n_in,
                              void* d_out, int out_size, void* d_ws, size_t ws_size,
                              hipStream_t stream) {
  const float* reps = (const float*)d_in[0];
  const int* labels = (const int*)d_in[1];
  float* out = (float*)d_out;
  char* ws = (char*)d_ws;
  // ws layout: Rb (bf16 normalized reps, 8 MiB) | row_pos | row_neg | done
  unsigned short* Rb = (unsigned short*)ws;
  float* row_pos = (float*)(ws + (size_t)NROW * DDIM * 2);
  float* row_neg = row_pos + NROW;
  int* done = (int*)(row_neg + NROW);

  k_prep<<<NROW / 4, 256, 0, stream>>>(reps, row_pos, Rb, done);
  k_row<<<512, 256, 0, stream>>>(Rb, labels, row_pos, row_neg, done, out);
  (void)in_sizes; (void)n_in; (void)out_size; (void)ws_size;
}

// Round 13
// 215.021 us; speedup vs baseline: 1.3404x; 1.3404x over previous
//
#include <hip/hip_runtime.h>

// SupProtoConLoss on MI355X — round 13.
// R12 post-mortem: `__shared__ int islast` pushed LDS 81920->82432 ->
// 1 block/CU (occupancy 10%, k_row exactly 2x R7). The fusion itself worked.
// Round 13 = R12 with the flag moved into Bs scratch (offset 512B, no alias
// with rp/rn) -> LDS exactly 81920 -> 2 blocks/CU restored. Nothing else.

#define NROW 8192
#define DDIM 512
#define NCLS 100
#define PANEL 64
#define JT 256  // cols per j-tile (4 waves x 64)
#define BK 32

typedef float f32x4 __attribute__((ext_vector_type(4)));
typedef short s16x8 __attribute__((ext_vector_type(8)));

#define GLOBAL_AS __attribute__((address_space(1)))
#define LDS_AS __attribute__((address_space(3)))

__device__ __forceinline__ unsigned short f2bf(float x) {
  unsigned int u = __builtin_bit_cast(unsigned int, x);
  u += 0x7FFFu + ((u >> 16) & 1u);  // round-to-nearest-even
  return (unsigned short)(u >> 16);
}

// One wave per row: L2-norm, scale, cast to bf16. Also zeroes row_pos/row_neg
// (16384 floats over 2048 blocks) and the done counter.
__global__ void __launch_bounds__(256) k_prep(
    const float* __restrict__ reps, float* __restrict__ row_pos,
    unsigned short* __restrict__ Rb, int* __restrict__ done) {
  const int wave = threadIdx.x >> 6;
  const int lane = threadIdx.x & 63;
  const int row = blockIdx.x * 4 + wave;
  if (threadIdx.x < 8) row_pos[blockIdx.x * 8 + threadIdx.x] = 0.0f;
  if (blockIdx.x == 0 && threadIdx.x == 0) *done = 0;
  const float* r = reps + (size_t)row * DDIM;
  float4 v0 = *(const float4*)(r + lane * 4);
  float4 v1 = *(const float4*)(r + 256 + lane * 4);
  float ss = v0.x * v0.x + v0.y * v0.y + v0.z * v0.z + v0.w * v0.w +
             v1.x * v1.x + v1.y * v1.y + v1.z * v1.z + v1.w * v1.w;
#pragma unroll
  for (int m = 1; m < 64; m <<= 1) ss += __shfl_xor(ss, m);
  const float scale = 1.0f / sqrtf(ss);  // norms ~22.6; 1e-8 clamp unreachable
  ushort4 a, b;
  a.x = f2bf(v0.x * scale); a.y = f2bf(v0.y * scale);
  a.z = f2bf(v0.z * scale); a.w = f2bf(v0.w * scale);
  b.x = f2bf(v1.x * scale); b.y = f2bf(v1.y * scale);
  b.z = f2bf(v1.z * scale); b.w = f2bf(v1.w * scale);
  *(ushort4*)(Rb + (size_t)row * DDIM + lane * 4) = a;
  *(ushort4*)(Rb + (size_t)row * DDIM + 256 + lane * 4) = b;
}

// Block = 64-row panel (p = bx>>2) x 2048-col slice (s = bx&3), 4 waves.
// Wave tile per jt: 64 rows x 64 cols = 4a x 4b of 16x16x32 MFMA.
// Last block to finish runs the loss finalize in-kernel.
__global__ void __launch_bounds__(256) k_row(
    const unsigned short* __restrict__ Rb, const int* __restrict__ labels,
    float* __restrict__ row_pos, float* __restrict__ row_neg,
    int* __restrict__ done, float* __restrict__ out) {
  const int bx = blockIdx.x;
  const int p = bx >> 2;   // row panel 0..127
  const int s = bx & 3;    // j slice 0..3 (fixed per XCD under %8 dispatch)
  const int i0 = p * PANEL;
  const int j0s = s * 2048;

  // As chunk-major [ch][row][k-in-chunk] (row stride 64B), 64 KB; Bs 16 KB.
  // Total EXACTLY 81920 B -> 2 blocks/CU (R12's +4B islast broke this).
  // Bs = epilogue scratch + last-block flag; As = finalize scratch.
  __shared__ __attribute__((aligned(16))) unsigned short As[16][PANEL][BK];
  __shared__ __attribute__((aligned(16))) unsigned short Bs[JT * BK];

  const int tid = threadIdx.x;
  const int lane = tid & 63;
  const int wave = tid >> 6;
  const int quad = lane >> 4, c16 = lane & 15;

  // ---- Stage A panel once, chunk-major: 64 instrs, 16 per wave.
#pragma unroll
  for (int t = 0; t < 16; ++t) {
    const int ii = wave * 16 + t;        // wave-uniform, 0..63
    const int ch = ii >> 2;
    const int rg = (ii & 3) * 16;
    const unsigned short* src =
        Rb + (size_t)(i0 + rg + (lane >> 2)) * DDIM + ch * BK + (lane & 3) * 8;
    __builtin_amdgcn_global_load_lds(
        (GLOBAL_AS void*)const_cast<unsigned short*>(src),
        (LDS_AS void*)(&As[ch][rg][0]), 16, 0, 0);
  }

  // Per-lane row labels and running row sums (live across the whole sweep).
  int li16[16];
  float ps16[16], ns16[16];
#pragma unroll
  for (int a = 0; a < 4; ++a)
#pragma unroll
    for (int r = 0; r < 4; ++r) {
      li16[a * 4 + r] = labels[i0 + a * 16 + quad * 4 + r];
      ps16[a * 4 + r] = 0.0f;
      ns16[a * 4 + r] = 0.0f;
    }

  const float C0 = -5.0f + 1e-7f;  // s = 5g - 5 + 1e-7 (static shift S=10)

  for (int jt = 0; jt < 8; ++jt) {
    const int j0 = j0s + jt * JT;
    int lj[4], gj[4];
#pragma unroll
    for (int b = 0; b < 4; ++b) {
      gj[b] = j0 + wave * 64 + b * 16 + c16;
      lj[b] = labels[gj[b]];
    }

    f32x4 acc[4][4];
#pragma unroll
    for (int a = 0; a < 4; ++a)
#pragma unroll
      for (int b = 0; b < 4; ++b) acc[a][b] = (f32x4)0.0f;

    for (int ch = 0; ch < 16; ++ch) {
      __syncthreads();  // Bs consumed (also drains A staging before 1st use)
#pragma unroll
      for (int t = 0; t < 4; ++t) {
        const int cb = wave * 64 + t * 256;  // wave-uniform
        const int sl = cb + lane;            // jcol = sl>>2, kc = sl&3
        const unsigned short* src =
            Rb + (size_t)(j0 + (sl >> 2)) * DDIM + ch * BK + (sl & 3) * 8;
        __builtin_amdgcn_global_load_lds(
            (GLOBAL_AS void*)const_cast<unsigned short*>(src),
            (LDS_AS void*)(Bs + cb * 8), 16, 0, 0);
      }
      __syncthreads();  // Bs ready

      s16x8 af[4], bfr[4];
#pragma unroll
      for (int a = 0; a < 4; ++a)
        af[a] = *(const s16x8*)(&As[ch][a * 16 + c16][quad * 8]);
#pragma unroll
      for (int b = 0; b < 4; ++b)
        bfr[b] = *(const s16x8*)(Bs + (wave * 64 + b * 16 + c16) * BK + quad * 8);
#pragma unroll
      for (int a = 0; a < 4; ++a)
#pragma unroll
        for (int b = 0; b < 4; ++b)
          acc[a][b] = __builtin_amdgcn_mfma_f32_16x16x32_bf16(af[a], bfr[b],
                                                              acc[a][b], 0, 0, 0);
    }

    // Fold this j-tile into register row sums (no atomics).
#pragma unroll
    for (int a = 0; a < 4; ++a) {
#pragma unroll
      for (int r = 0; r < 4; ++r) {
        const int gi = i0 + a * 16 + quad * 4 + r;
        const int li = li16[a * 4 + r];
        float ps = 0.0f, ns = 0.0f;
#pragma unroll
        for (int b = 0; b < 4; ++b) {
          const float g = acc[a][b][r];
          const float sv = fmaf(g, 5.0f, C0);
          const float ev = __expf(sv);
          const bool same = (li == lj[b]);
          ps += (same && gi != gj[b]) ? sv : 0.0f;
          ns += same ? 0.0f : ev;
        }
        ps16[a * 4 + r] += ps;
        ns16[a * 4 + r] += ns;
      }
    }
  }

  // ---- Block epilogue: reduce per-lane sums -> 64 rows, 2 atomics each.
  __syncthreads();
  float* rp = (float*)Bs;           // 64 floats
  float* rn = rp + 64;              // 64 floats
  int* flag = (int*)(rn + 64);      // Bs+512B; no alias with rp/rn
  if (tid < 128) rp[tid] = 0.0f;
  __syncthreads();
#pragma unroll
  for (int a = 0; a < 4; ++a) {
#pragma unroll
    for (int r = 0; r < 4; ++r) {
      float ps = ps16[a * 4 + r], ns = ns16[a * 4 + r];
#pragma unroll
      for (int m = 1; m < 16; m <<= 1) {  // reduce across the 16 c16 lanes
        ps += __shfl_xor(ps, m);
        ns += __shfl_xor(ns, m);
      }
      if (c16 == 0) {  // 4-way wave contention, once per block: trivial
        atomicAdd(&rp[a * 16 + quad * 4 + r], ps);
        atomicAdd(&rn[a * 16 + quad * 4 + r], ns);
      }
    }
  }
  __syncthreads();
  if (tid < 64) {
    atomicAdd(&row_pos[i0 + tid], rp[tid]);   // 4 adds per address chip-wide
    atomicAdd(&row_neg[i0 + tid], rn[tid]);
  }

  // ---- Last-block finalize (no co-residency / dispatch-order assumption).
  __syncthreads();  // vmcnt(0) drain: all waves' row atomics completed
  __threadfence();  // release before the done increment
  if (tid == 0)
    *flag = (atomicAdd(done, 1) == (int)gridDim.x - 1) ? 1 : 0;
  __syncthreads();
  if (*flag == 0) return;
  __threadfence();  // acquire side

  int* hcnt = (int*)&As[0][0][0];        // reuse As as finalize scratch
  float* fsum = (float*)&As[1][0][0];    // 4 partial sums
  float* fcnt = fsum + 4;
  if (tid < NCLS) hcnt[tid] = 0;
  __syncthreads();
  for (int i = tid; i < NROW; i += 256) atomicAdd(&hcnt[labels[i]], 1);
  __syncthreads();
  float lsum = 0.0f, lcnt = 0.0f;
  for (int i = tid; i < NROW; i += 256) {
    // atomic reads: device-coherent (plain loads could see stale per-XCD L2)
    const float rpv = atomicAdd(&row_pos[i], 0.0f);
    const float rnv = atomicAdd(&row_neg[i], 0.0f);
    const float c = (float)(hcnt[labels[i]] - 1);
    const float pos = rpv / (c + 1e-8f);
    const float loss = -pos + logf(rnv + 1e-8f);
    if (loss > 0.0f) { lsum += loss; lcnt += 1.0f; }
  }
#pragma unroll
  for (int m = 1; m < 64; m <<= 1) {
    lsum += __shfl_xor(lsum, m);
    lcnt += __shfl_xor(lcnt, m);
  }
  if (lane == 0) { fsum[wave] = lsum; fcnt[wave] = lcnt; }
  __syncthreads();
  if (tid == 0) {
    float S = 0.0f, C = 0.0f;
#pragma unroll
    for (int w = 0; w < 4; ++w) { S += fsum[w]; C += fcnt[w]; }
    out[0] = S / (C + 1e-8f);
  }
}

extern "C" void kernel_launch(void* const* d_in, const int* in_sizes, int n_in,
                              void* d_out, int out_size, void* d_ws, size_t ws_size,
                              hipStream_t stream) {
  const float* reps = (const float*)d_in[0];
  const int* labels = (const int*)d_in[1];
  float* out = (float*)d_out;
  char* ws = (char*)d_ws;
  // ws layout: Rb (bf16 normalized reps, 8 MiB) | row_pos | row_neg | done
  unsigned short* Rb = (unsigned short*)ws;
  float* row_pos = (float*)(ws + (size_t)NROW * DDIM * 2);
  float* row_neg = row_pos + NROW;
  int* done = (int*)(row_neg + NROW);

  k_prep<<<NROW / 4, 256, 0, stream>>>(reps, row_pos, Rb, done);
  k_row<<<512, 256, 0, stream>>>(Rb, labels, row_pos, row_neg, done, out);
  (void)in_sizes; (void)n_in; (void)out_size; (void)ws_size;
}

// Round 14
// 207.497 us; speedup vs baseline: 1.3891x; 1.0363x over previous
//
#include <hip/hip_runtime.h>

// SupProtoConLoss on MI355X — round 14.
// R13 post-mortem: engine unchanged at ~110us (MfmaUtil dilution 24.7*(110/169)
// =16.1 matches exactly); the +59us is the serial last-block finalize whose
// 2x32 dependent device-scope atomicAdd(p,0.f) reads serialize at far-
// coherence latency. The release (syncthreads drains vmcnt + threadfence) /
// acquire (threadfence after done==511) pair already makes plain loads legal.
// Round 14: finalize reads row sums with plain float4 loads + __logf.
// Engine verbatim from R7/R13. LDS exactly 81920 (2 blocks/CU).

#define NROW 8192
#define DDIM 512
#define NCLS 100
#define PANEL 64
#define JT 256  // cols per j-tile (4 waves x 64)
#define BK 32

typedef float f32x4 __attribute__((ext_vector_type(4)));
typedef short s16x8 __attribute__((ext_vector_type(8)));

#define GLOBAL_AS __attribute__((address_space(1)))
#define LDS_AS __attribute__((address_space(3)))

__device__ __forceinline__ unsigned short f2bf(float x) {
  unsigned int u = __builtin_bit_cast(unsigned int, x);
  u += 0x7FFFu + ((u >> 16) & 1u);  // round-to-nearest-even
  return (unsigned short)(u >> 16);
}

// One wave per row: L2-norm, scale, cast to bf16. Also zeroes row_pos/row_neg
// (16384 floats over 2048 blocks) and the done counter.
__global__ void __launch_bounds__(256) k_prep(
    const float* __restrict__ reps, float* __restrict__ row_pos,
    unsigned short* __restrict__ Rb, int* __restrict__ done) {
  const int wave = threadIdx.x >> 6;
  const int lane = threadIdx.x & 63;
  const int row = blockIdx.x * 4 + wave;
  if (threadIdx.x < 8) row_pos[blockIdx.x * 8 + threadIdx.x] = 0.0f;
  if (blockIdx.x == 0 && threadIdx.x == 0) *done = 0;
  const float* r = reps + (size_t)row * DDIM;
  float4 v0 = *(const float4*)(r + lane * 4);
  float4 v1 = *(const float4*)(r + 256 + lane * 4);
  float ss = v0.x * v0.x + v0.y * v0.y + v0.z * v0.z + v0.w * v0.w +
             v1.x * v1.x + v1.y * v1.y + v1.z * v1.z + v1.w * v1.w;
#pragma unroll
  for (int m = 1; m < 64; m <<= 1) ss += __shfl_xor(ss, m);
  const float scale = 1.0f / sqrtf(ss);  // norms ~22.6; 1e-8 clamp unreachable
  ushort4 a, b;
  a.x = f2bf(v0.x * scale); a.y = f2bf(v0.y * scale);
  a.z = f2bf(v0.z * scale); a.w = f2bf(v0.w * scale);
  b.x = f2bf(v1.x * scale); b.y = f2bf(v1.y * scale);
  b.z = f2bf(v1.z * scale); b.w = f2bf(v1.w * scale);
  *(ushort4*)(Rb + (size_t)row * DDIM + lane * 4) = a;
  *(ushort4*)(Rb + (size_t)row * DDIM + 256 + lane * 4) = b;
}

// Block = 64-row panel (p = bx>>2) x 2048-col slice (s = bx&3), 4 waves.
// Wave tile per jt: 64 rows x 64 cols = 4a x 4b of 16x16x32 MFMA.
// Last block to finish runs the loss finalize in-kernel.
__global__ void __launch_bounds__(256) k_row(
    const unsigned short* __restrict__ Rb, const int* __restrict__ labels,
    float* __restrict__ row_pos, float* __restrict__ row_neg,
    int* __restrict__ done, float* __restrict__ out) {
  const int bx = blockIdx.x;
  const int p = bx >> 2;   // row panel 0..127
  const int s = bx & 3;    // j slice 0..3 (fixed per XCD under %8 dispatch)
  const int i0 = p * PANEL;
  const int j0s = s * 2048;

  // As chunk-major [ch][row][k-in-chunk] (row stride 64B), 64 KB; Bs 16 KB.
  // Total EXACTLY 81920 B -> 2 blocks/CU. Bs = epilogue scratch + flag;
  // As = finalize scratch. DO NOT add LDS.
  __shared__ __attribute__((aligned(16))) unsigned short As[16][PANEL][BK];
  __shared__ __attribute__((aligned(16))) unsigned short Bs[JT * BK];

  const int tid = threadIdx.x;
  const int lane = tid & 63;
  const int wave = tid >> 6;
  const int quad = lane >> 4, c16 = lane & 15;

  // ---- Stage A panel once, chunk-major: 64 instrs, 16 per wave.
#pragma unroll
  for (int t = 0; t < 16; ++t) {
    const int ii = wave * 16 + t;        // wave-uniform, 0..63
    const int ch = ii >> 2;
    const int rg = (ii & 3) * 16;
    const unsigned short* src =
        Rb + (size_t)(i0 + rg + (lane >> 2)) * DDIM + ch * BK + (lane & 3) * 8;
    __builtin_amdgcn_global_load_lds(
        (GLOBAL_AS void*)const_cast<unsigned short*>(src),
        (LDS_AS void*)(&As[ch][rg][0]), 16, 0, 0);
  }

  // Per-lane row labels and running row sums (live across the whole sweep).
  int li16[16];
  float ps16[16], ns16[16];
#pragma unroll
  for (int a = 0; a < 4; ++a)
#pragma unroll
    for (int r = 0; r < 4; ++r) {
      li16[a * 4 + r] = labels[i0 + a * 16 + quad * 4 + r];
      ps16[a * 4 + r] = 0.0f;
      ns16[a * 4 + r] = 0.0f;
    }

  const float C0 = -5.0f + 1e-7f;  // s = 5g - 5 + 1e-7 (static shift S=10)

  for (int jt = 0; jt < 8; ++jt) {
    const int j0 = j0s + jt * JT;
    int lj[4], gj[4];
#pragma unroll
    for (int b = 0; b < 4; ++b) {
      gj[b] = j0 + wave * 64 + b * 16 + c16;
      lj[b] = labels[gj[b]];
    }

    f32x4 acc[4][4];
#pragma unroll
    for (int a = 0; a < 4; ++a)
#pragma unroll
      for (int b = 0; b < 4; ++b) acc[a][b] = (f32x4)0.0f;

    for (int ch = 0; ch < 16; ++ch) {
      __syncthreads();  // Bs consumed (also drains A staging before 1st use)
#pragma unroll
      for (int t = 0; t < 4; ++t) {
        const int cb = wave * 64 + t * 256;  // wave-uniform
        const int sl = cb + lane;            // jcol = sl>>2, kc = sl&3
        const unsigned short* src =
            Rb + (size_t)(j0 + (sl >> 2)) * DDIM + ch * BK + (sl & 3) * 8;
        __builtin_amdgcn_global_load_lds(
            (GLOBAL_AS void*)const_cast<unsigned short*>(src),
            (LDS_AS void*)(Bs + cb * 8), 16, 0, 0);
      }
      __syncthreads();  // Bs ready

      s16x8 af[4], bfr[4];
#pragma unroll
      for (int a = 0; a < 4; ++a)
        af[a] = *(const s16x8*)(&As[ch][a * 16 + c16][quad * 8]);
#pragma unroll
      for (int b = 0; b < 4; ++b)
        bfr[b] = *(const s16x8*)(Bs + (wave * 64 + b * 16 + c16) * BK + quad * 8);
#pragma unroll
      for (int a = 0; a < 4; ++a)
#pragma unroll
        for (int b = 0; b < 4; ++b)
          acc[a][b] = __builtin_amdgcn_mfma_f32_16x16x32_bf16(af[a], bfr[b],
                                                              acc[a][b], 0, 0, 0);
    }

    // Fold this j-tile into register row sums (no atomics).
#pragma unroll
    for (int a = 0; a < 4; ++a) {
#pragma unroll
      for (int r = 0; r < 4; ++r) {
        const int gi = i0 + a * 16 + quad * 4 + r;
        const int li = li16[a * 4 + r];
        float ps = 0.0f, ns = 0.0f;
#pragma unroll
        for (int b = 0; b < 4; ++b) {
          const float g = acc[a][b][r];
          const float sv = fmaf(g, 5.0f, C0);
          const float ev = __expf(sv);
          const bool same = (li == lj[b]);
          ps += (same && gi != gj[b]) ? sv : 0.0f;
          ns += same ? 0.0f : ev;
        }
        ps16[a * 4 + r] += ps;
        ns16[a * 4 + r] += ns;
      }
    }
  }

  // ---- Block epilogue: reduce per-lane sums -> 64 rows, 2 atomics each.
  __syncthreads();
  float* rp = (float*)Bs;           // 64 floats
  float* rn = rp + 64;              // 64 floats
  int* flag = (int*)(rn + 64);      // Bs+512B; no alias with rp/rn
  if (tid < 128) rp[tid] = 0.0f;
  __syncthreads();
#pragma unroll
  for (int a = 0; a < 4; ++a) {
#pragma unroll
    for (int r = 0; r < 4; ++r) {
      float ps = ps16[a * 4 + r], ns = ns16[a * 4 + r];
#pragma unroll
      for (int m = 1; m < 16; m <<= 1) {  // reduce across the 16 c16 lanes
        ps += __shfl_xor(ps, m);
        ns += __shfl_xor(ns, m);
      }
      if (c16 == 0) {  // 4-way wave contention, once per block: trivial
        atomicAdd(&rp[a * 16 + quad * 4 + r], ps);
        atomicAdd(&rn[a * 16 + quad * 4 + r], ns);
      }
    }
  }
  __syncthreads();
  if (tid < 64) {
    atomicAdd(&row_pos[i0 + tid], rp[tid]);   // 4 adds per address chip-wide
    atomicAdd(&row_neg[i0 + tid], rn[tid]);
  }

  // ---- Last-block finalize (no co-residency / dispatch-order assumption).
  __syncthreads();  // barrier drains vmcnt: all waves' row atomics complete
  __threadfence();  // release
  if (tid == 0)
    *flag = (atomicAdd(done, 1) == (int)gridDim.x - 1) ? 1 : 0;
  __syncthreads();
  if (*flag == 0) return;
  __threadfence();  // acquire: released writes now visible to PLAIN loads

  int* hcnt = (int*)&As[0][0][0];        // reuse As as finalize scratch
  float* fsum = (float*)&As[1][0][0];    // 4 partial sums
  float* fcnt = fsum + 4;
  if (tid < NCLS) hcnt[tid] = 0;
  __syncthreads();
  for (int i = tid; i < NROW; i += 256) atomicAdd(&hcnt[labels[i]], 1);
  __syncthreads();
  float lsum = 0.0f, lcnt = 0.0f;
  // Vectorized plain loads (legal after acquire fence); 8 iters/thread.
  for (int i4 = tid * 4; i4 < NROW; i4 += 1024) {
    const float4 rp4 = *(const float4*)(row_pos + i4);
    const float4 rn4 = *(const float4*)(row_neg + i4);
    const int4 lb4 = *(const int4*)(labels + i4);
    const float pv[4] = {rp4.x, rp4.y, rp4.z, rp4.w};
    const float nv[4] = {rn4.x, rn4.y, rn4.z, rn4.w};
    const int lb[4] = {lb4.x, lb4.y, lb4.z, lb4.w};
#pragma unroll
    for (int u = 0; u < 4; ++u) {
      const float c = (float)(hcnt[lb[u]] - 1);
      const float pos = pv[u] / (c + 1e-8f);
      const float loss = -pos + __logf(nv[u] + 1e-8f);
      if (loss > 0.0f) { lsum += loss; lcnt += 1.0f; }
    }
  }
#pragma unroll
  for (int m = 1; m < 64; m <<= 1) {
    lsum += __shfl_xor(lsum, m);
    lcnt += __shfl_xor(lcnt, m);
  }
  if (lane == 0) { fsum[wave] = lsum; fcnt[wave] = lcnt; }
  __syncthreads();
  if (tid == 0) {
    float S = 0.0f, C = 0.0f;
#pragma unroll
    for (int w = 0; w < 4; ++w) { S += fsum[w]; C += fcnt[w]; }
    out[0] = S / (C + 1e-8f);
  }
}

extern "C" void kernel_launch(void* const* d_in, const int* in_sizes, int n_in,
                              void* d_out, int out_size, void* d_ws, size_t ws_size,
                              hipStream_t stream) {
  const float* reps = (const float*)d_in[0];
  const int* labels = (const int*)d_in[1];
  float* out = (float*)d_out;
  char* ws = (char*)d_ws;
  // ws layout: Rb (bf16 normalized reps, 8 MiB) | row_pos | row_neg | done
  unsigned short* Rb = (unsigned short*)ws;
  float* row_pos = (float*)(ws + (size_t)NROW * DDIM * 2);
  float* row_neg = row_pos + NROW;
  int* done = (int*)(row_neg + NROW);

  k_prep<<<NROW / 4, 256, 0, stream>>>(reps, row_pos, Rb, done);
  k_row<<<512, 256, 0, stream>>>(Rb, labels, row_pos, row_neg, done, out);
  (void)in_sizes; (void)n_in; (void)out_size; (void)ws_size;
}

// Round 15
// 181.435 us; speedup vs baseline: 1.5886x; 1.1436x over previous
//
#include <hip/hip_runtime.h>

// SupProtoConLoss on MI355X — round 15.
// R14 post-mortem: plain-load finalize recovered 17us; ~42us tail remains.
// Diagnosis: __threadfence() is a FULL agent fence (buffer_wbl2 + buffer_inv)
// executed by ALL 512 blocks at finish -> each invalidates its XCD L2 under
// still-running siblings (re-fetch from L3: latency up, FETCH_SIZE unchanged
// -- matches counters). The release side is redundant: k_row's only global
// writes are device-scope atomics, ack'd at the coherence point when the
// pre-done __syncthreads drains vmcnt(0); program order covers the rest.
// Round 15 (single change): drop the per-block release fence; keep ONE
// acquire __threadfence in the winner block only. Engine R7-verbatim.

#define NROW 8192
#define DDIM 512
#define NCLS 100
#define PANEL 64
#define JT 256  // cols per j-tile (4 waves x 64)
#define BK 32

typedef float f32x4 __attribute__((ext_vector_type(4)));
typedef short s16x8 __attribute__((ext_vector_type(8)));

#define GLOBAL_AS __attribute__((address_space(1)))
#define LDS_AS __attribute__((address_space(3)))

__device__ __forceinline__ unsigned short f2bf(float x) {
  unsigned int u = __builtin_bit_cast(unsigned int, x);
  u += 0x7FFFu + ((u >> 16) & 1u);  // round-to-nearest-even
  return (unsigned short)(u >> 16);
}

// One wave per row: L2-norm, scale, cast to bf16. Also zeroes row_pos/row_neg
// (16384 floats over 2048 blocks) and the done counter.
__global__ void __launch_bounds__(256) k_prep(
    const float* __restrict__ reps, float* __restrict__ row_pos,
    unsigned short* __restrict__ Rb, int* __restrict__ done) {
  const int wave = threadIdx.x >> 6;
  const int lane = threadIdx.x & 63;
  const int row = blockIdx.x * 4 + wave;
  if (threadIdx.x < 8) row_pos[blockIdx.x * 8 + threadIdx.x] = 0.0f;
  if (blockIdx.x == 0 && threadIdx.x == 0) *done = 0;
  const float* r = reps + (size_t)row * DDIM;
  float4 v0 = *(const float4*)(r + lane * 4);
  float4 v1 = *(const float4*)(r + 256 + lane * 4);
  float ss = v0.x * v0.x + v0.y * v0.y + v0.z * v0.z + v0.w * v0.w +
             v1.x * v1.x + v1.y * v1.y + v1.z * v1.z + v1.w * v1.w;
#pragma unroll
  for (int m = 1; m < 64; m <<= 1) ss += __shfl_xor(ss, m);
  const float scale = 1.0f / sqrtf(ss);  // norms ~22.6; 1e-8 clamp unreachable
  ushort4 a, b;
  a.x = f2bf(v0.x * scale); a.y = f2bf(v0.y * scale);
  a.z = f2bf(v0.z * scale); a.w = f2bf(v0.w * scale);
  b.x = f2bf(v1.x * scale); b.y = f2bf(v1.y * scale);
  b.z = f2bf(v1.z * scale); b.w = f2bf(v1.w * scale);
  *(ushort4*)(Rb + (size_t)row * DDIM + lane * 4) = a;
  *(ushort4*)(Rb + (size_t)row * DDIM + 256 + lane * 4) = b;
}

// Block = 64-row panel (p = bx>>2) x 2048-col slice (s = bx&3), 4 waves.
// Wave tile per jt: 64 rows x 64 cols = 4a x 4b of 16x16x32 MFMA.
// Last block to finish runs the loss finalize in-kernel.
__global__ void __launch_bounds__(256) k_row(
    const unsigned short* __restrict__ Rb, const int* __restrict__ labels,
    float* __restrict__ row_pos, float* __restrict__ row_neg,
    int* __restrict__ done, float* __restrict__ out) {
  const int bx = blockIdx.x;
  const int p = bx >> 2;   // row panel 0..127
  const int s = bx & 3;    // j slice 0..3 (fixed per XCD under %8 dispatch)
  const int i0 = p * PANEL;
  const int j0s = s * 2048;

  // As chunk-major [ch][row][k-in-chunk] (row stride 64B), 64 KB; Bs 16 KB.
  // Total EXACTLY 81920 B -> 2 blocks/CU. Bs = epilogue scratch + flag;
  // As = finalize scratch. DO NOT add LDS.
  __shared__ __attribute__((aligned(16))) unsigned short As[16][PANEL][BK];
  __shared__ __attribute__((aligned(16))) unsigned short Bs[JT * BK];

  const int tid = threadIdx.x;
  const int lane = tid & 63;
  const int wave = tid >> 6;
  const int quad = lane >> 4, c16 = lane & 15;

  // ---- Stage A panel once, chunk-major: 64 instrs, 16 per wave.
#pragma unroll
  for (int t = 0; t < 16; ++t) {
    const int ii = wave * 16 + t;        // wave-uniform, 0..63
    const int ch = ii >> 2;
    const int rg = (ii & 3) * 16;
    const unsigned short* src =
        Rb + (size_t)(i0 + rg + (lane >> 2)) * DDIM + ch * BK + (lane & 3) * 8;
    __builtin_amdgcn_global_load_lds(
        (GLOBAL_AS void*)const_cast<unsigned short*>(src),
        (LDS_AS void*)(&As[ch][rg][0]), 16, 0, 0);
  }

  // Per-lane row labels and running row sums (live across the whole sweep).
  int li16[16];
  float ps16[16], ns16[16];
#pragma unroll
  for (int a = 0; a < 4; ++a)
#pragma unroll
    for (int r = 0; r < 4; ++r) {
      li16[a * 4 + r] = labels[i0 + a * 16 + quad * 4 + r];
      ps16[a * 4 + r] = 0.0f;
      ns16[a * 4 + r] = 0.0f;
    }

  const float C0 = -5.0f + 1e-7f;  // s = 5g - 5 + 1e-7 (static shift S=10)

  for (int jt = 0; jt < 8; ++jt) {
    const int j0 = j0s + jt * JT;
    int lj[4], gj[4];
#pragma unroll
    for (int b = 0; b < 4; ++b) {
      gj[b] = j0 + wave * 64 + b * 16 + c16;
      lj[b] = labels[gj[b]];
    }

    f32x4 acc[4][4];
#pragma unroll
    for (int a = 0; a < 4; ++a)
#pragma unroll
      for (int b = 0; b < 4; ++b) acc[a][b] = (f32x4)0.0f;

    for (int ch = 0; ch < 16; ++ch) {
      __syncthreads();  // Bs consumed (also drains A staging before 1st use)
#pragma unroll
      for (int t = 0; t < 4; ++t) {
        const int cb = wave * 64 + t * 256;  // wave-uniform
        const int sl = cb + lane;            // jcol = sl>>2, kc = sl&3
        const unsigned short* src =
            Rb + (size_t)(j0 + (sl >> 2)) * DDIM + ch * BK + (sl & 3) * 8;
        __builtin_amdgcn_global_load_lds(
            (GLOBAL_AS void*)const_cast<unsigned short*>(src),
            (LDS_AS void*)(Bs + cb * 8), 16, 0, 0);
      }
      __syncthreads();  // Bs ready

      s16x8 af[4], bfr[4];
#pragma unroll
      for (int a = 0; a < 4; ++a)
        af[a] = *(const s16x8*)(&As[ch][a * 16 + c16][quad * 8]);
#pragma unroll
      for (int b = 0; b < 4; ++b)
        bfr[b] = *(const s16x8*)(Bs + (wave * 64 + b * 16 + c16) * BK + quad * 8);
#pragma unroll
      for (int a = 0; a < 4; ++a)
#pragma unroll
        for (int b = 0; b < 4; ++b)
          acc[a][b] = __builtin_amdgcn_mfma_f32_16x16x32_bf16(af[a], bfr[b],
                                                              acc[a][b], 0, 0, 0);
    }

    // Fold this j-tile into register row sums (no atomics).
#pragma unroll
    for (int a = 0; a < 4; ++a) {
#pragma unroll
      for (int r = 0; r < 4; ++r) {
        const int gi = i0 + a * 16 + quad * 4 + r;
        const int li = li16[a * 4 + r];
        float ps = 0.0f, ns = 0.0f;
#pragma unroll
        for (int b = 0; b < 4; ++b) {
          const float g = acc[a][b][r];
          const float sv = fmaf(g, 5.0f, C0);
          const float ev = __expf(sv);
          const bool same = (li == lj[b]);
          ps += (same && gi != gj[b]) ? sv : 0.0f;
          ns += same ? 0.0f : ev;
        }
        ps16[a * 4 + r] += ps;
        ns16[a * 4 + r] += ns;
      }
    }
  }

  // ---- Block epilogue: reduce per-lane sums -> 64 rows, 2 atomics each.
  __syncthreads();
  float* rp = (float*)Bs;           // 64 floats
  float* rn = rp + 64;              // 64 floats
  int* flag = (int*)(rn + 64);      // Bs+512B; no alias with rp/rn
  if (tid < 128) rp[tid] = 0.0f;
  __syncthreads();
#pragma unroll
  for (int a = 0; a < 4; ++a) {
#pragma unroll
    for (int r = 0; r < 4; ++r) {
      float ps = ps16[a * 4 + r], ns = ns16[a * 4 + r];
#pragma unroll
      for (int m = 1; m < 16; m <<= 1) {  // reduce across the 16 c16 lanes
        ps += __shfl_xor(ps, m);
        ns += __shfl_xor(ns, m);
      }
      if (c16 == 0) {  // 4-way wave contention, once per block: trivial
        atomicAdd(&rp[a * 16 + quad * 4 + r], ps);
        atomicAdd(&rn[a * 16 + quad * 4 + r], ns);
      }
    }
  }
  __syncthreads();
  if (tid < 64) {
    atomicAdd(&row_pos[i0 + tid], rp[tid]);   // device-scope, 4/address
    atomicAdd(&row_neg[i0 + tid], rn[tid]);
  }

  // ---- Last-block finalize. NO per-block fence: the barrier below drains
  // vmcnt(0), so all row atomics are ack'd at the device coherence point
  // before any thread issues the done increment (program order). A release
  // __threadfence here would buffer_inv each XCD's L2 under running blocks
  // (the R13/R14 42us tail).
  __syncthreads();
  if (tid == 0)
    *flag = (atomicAdd(done, 1) == (int)gridDim.x - 1) ? 1 : 0;
  __syncthreads();
  if (*flag == 0) return;
  __threadfence();  // acquire (winner only): invalidate stale L1/L2 lines

  int* hcnt = (int*)&As[0][0][0];        // reuse As as finalize scratch
  float* fsum = (float*)&As[1][0][0];    // 4 partial sums
  float* fcnt = fsum + 4;
  if (tid < NCLS) hcnt[tid] = 0;
  __syncthreads();
  for (int i = tid; i < NROW; i += 256) atomicAdd(&hcnt[labels[i]], 1);
  __syncthreads();
  float lsum = 0.0f, lcnt = 0.0f;
  // Vectorized plain loads (legal after acquire fence); 8 iters/thread.
  for (int i4 = tid * 4; i4 < NROW; i4 += 1024) {
    const float4 rp4 = *(const float4*)(row_pos + i4);
    const float4 rn4 = *(const float4*)(row_neg + i4);
    const int4 lb4 = *(const int4*)(labels + i4);
    const float pv[4] = {rp4.x, rp4.y, rp4.z, rp4.w};
    const float nv[4] = {rn4.x, rn4.y, rn4.z, rn4.w};
    const int lb[4] = {lb4.x, lb4.y, lb4.z, lb4.w};
#pragma unroll
    for (int u = 0; u < 4; ++u) {
      const float c = (float)(hcnt[lb[u]] - 1);
      const float pos = pv[u] / (c + 1e-8f);
      const float loss = -pos + __logf(nv[u] + 1e-8f);
      if (loss > 0.0f) { lsum += loss; lcnt += 1.0f; }
    }
  }
#pragma unroll
  for (int m = 1; m < 64; m <<= 1) {
    lsum += __shfl_xor(lsum, m);
    lcnt += __shfl_xor(lcnt, m);
  }
  if (lane == 0) { fsum[wave] = lsum; fcnt[wave] = lcnt; }
  __syncthreads();
  if (tid == 0) {
    float S = 0.0f, C = 0.0f;
#pragma unroll
    for (int w = 0; w < 4; ++w) { S += fsum[w]; C += fcnt[w]; }
    out[0] = S / (C + 1e-8f);
  }
}

extern "C" void kernel_launch(void* const* d_in, const int* in_sizes, int n_in,
                              void* d_out, int out_size, void* d_ws, size_t ws_size,
                              hipStream_t stream) {
  const float* reps = (const float*)d_in[0];
  const int* labels = (const int*)d_in[1];
  float* out = (float*)d_out;
  char* ws = (char*)d_ws;
  // ws layout: Rb (bf16 normalized reps, 8 MiB) | row_pos | row_neg | done
  unsigned short* Rb = (unsigned short*)ws;
  float* row_pos = (float*)(ws + (size_t)NROW * DDIM * 2);
  float* row_neg = row_pos + NROW;
  int* done = (int*)(row_neg + NROW);

  k_prep<<<NROW / 4, 256, 0, stream>>>(reps, row_pos, Rb, done);
  k_row<<<512, 256, 0, stream>>>(Rb, labels, row_pos, row_neg, done, out);
  (void)in_sizes; (void)n_in; (void)out_size; (void)ws_size;
}